// Round 1
// 780.816 us; speedup vs baseline: 1.0397x; 1.0397x over previous
//
#include <hip/hip_runtime.h>
#include <hip/hip_bf16.h>
#include <stdint.h>

// ---------------------------------------------------------------------------
// R3: heads GEMMs moved to a 256x256-tile, BK=64, 8-wave, 4-phase/K-tile
// schedule with counted vmcnt (T3+T4), st_16x32 LDS XOR-swizzle via
// pre-swizzled global source (T2, rule 21), s_setprio around MFMA clusters
// (T5), and bijective XCD block swizzle (T1). Trunk GEMMs + transposes
// unchanged from R2b.
// ---------------------------------------------------------------------------

typedef __bf16 bf16x8 __attribute__((ext_vector_type(8)));
typedef float  floatx4 __attribute__((ext_vector_type(4)));
typedef unsigned short ushortx4 __attribute__((ext_vector_type(4)));
typedef unsigned short ushortx8 __attribute__((ext_vector_type(8)));

typedef __attribute__((address_space(1))) void as1_void;
typedef __attribute__((address_space(3))) void as3_void;

__device__ __forceinline__ void gld_lds16(const void* g, void* l) {
    __builtin_amdgcn_global_load_lds((as1_void*)g, (as3_void*)l, 16, 0, 0);
}

__device__ __forceinline__ unsigned short f2bf(float f) {
    __hip_bfloat16 h = __float2bfloat16(f);
    unsigned short s;
    __builtin_memcpy(&s, &h, 2);
    return s;
}

// ---------------------------------------------------------------------------
// Old 128x128 kernel (kept for the two trunk GEMMs).
// MODE 0: out = relu((acc + b - mean)*gamma*rsqrt(var+eps) + beta) -> bf16
// MODE 1: out = relu(acc + bias) -> bf16
// MODE 2: out = acc + bias -> fp32
// ---------------------------------------------------------------------------
template <int MODE, typename OutT>
__global__ __launch_bounds__(256, 2)
void gemm_bt(const short* __restrict__ A, int lda, long aBatch,
             const short* __restrict__ B, int ldb, long bBatch,
             OutT* __restrict__ C, int ldc, long cBatch,
             int K, int ntilesN,
             const float* __restrict__ p0, const float* __restrict__ p1,
             const float* __restrict__ p2, const float* __restrict__ p3,
             const float* __restrict__ p4, int pBatch)
{
    __shared__ short As[128 * 32];
    __shared__ short Bs[128 * 32];

    const int tid  = threadIdx.x;
    const int w    = tid >> 6;
    const int l    = tid & 63;
    const int head = blockIdx.y;
    const int mt   = blockIdx.x / ntilesN;
    const int nt   = blockIdx.x % ntilesN;
    const int m0   = mt * 128;
    const int n0   = nt * 128;

    A += (long)head * aBatch;
    B += (long)head * bBatch;
    C += (long)head * cBatch;
    const float* pb = p0 + (long)head * pBatch;

    const int wm   = (w >> 1) * 64;
    const int wn   = (w & 1) * 64;
    const int lrow = l & 15;
    const int lk   = (l >> 4) * 8;

    floatx4 acc[4][4] = {};

    const int srow = l >> 2;
    const int scol = (l & 3) * 8;
    const short* Ag = A + (long)(m0 + w * 16 + srow) * lda + scol;
    const short* Bg = B + (long)(n0 + w * 16 + srow) * ldb + scol;
    const long a64 = (long)64 * lda;
    const long b64 = (long)64 * ldb;
    short* AsW0 = &As[(w * 16) * 32];
    short* AsW1 = &As[(64 + w * 16) * 32];
    short* BsW0 = &Bs[(w * 16) * 32];
    short* BsW1 = &Bs[(64 + w * 16) * 32];

    for (int k0 = 0; k0 < K; k0 += 32) {
        gld_lds16(Ag + k0,       AsW0);
        gld_lds16(Ag + a64 + k0, AsW1);
        gld_lds16(Bg + k0,       BsW0);
        gld_lds16(Bg + b64 + k0, BsW1);
        __syncthreads();

        bf16x8 af[4], bfr[4];
#pragma unroll
        for (int i = 0; i < 4; ++i)
            af[i] = *(const bf16x8*)&As[(wm + i * 16 + lrow) * 32 + lk];
#pragma unroll
        for (int j = 0; j < 4; ++j)
            bfr[j] = *(const bf16x8*)&Bs[(wn + j * 16 + lrow) * 32 + lk];

#pragma unroll
        for (int i = 0; i < 4; ++i)
#pragma unroll
            for (int j = 0; j < 4; ++j)
                acc[i][j] = __builtin_amdgcn_mfma_f32_16x16x32_bf16(
                    af[i], bfr[j], acc[i][j], 0, 0, 0);
        __syncthreads();
    }

    const int erow = (l >> 4) * 4;
    const int ecol = l & 15;
#pragma unroll
    for (int j = 0; j < 4; ++j) {
        const int nj = n0 + wn + j * 16 + ecol;
        float scale = 1.f, shift;
        if constexpr (MODE == 0) {
            const float s = p1[nj] * rsqrtf(p4[nj] + 1e-5f);
            scale = s;
            shift = (pb[nj] - p3[nj]) * s + p2[nj];
        } else {
            shift = pb[nj];
        }
#pragma unroll
        for (int i = 0; i < 4; ++i) {
            const long mi = m0 + wm + i * 16 + erow;
#pragma unroll
            for (int r = 0; r < 4; ++r) {
                float v = acc[i][j][r] * scale + shift;
                if constexpr (MODE != 2) v = fmaxf(v, 0.f);
                const long idx = (mi + r) * (long)ldc + nj;
                if constexpr (sizeof(OutT) == 2) C[idx] = (OutT)f2bf(v);
                else                             C[idx] = (OutT)v;
            }
        }
    }
}

// ---------------------------------------------------------------------------
// New 256x256 8-wave kernel for the head GEMMs.
//
// Geometry: BM=BN=256, BK=64, 512 threads = 8 waves (2M x 4N), per-wave
// output 128x64 (8x4 fragments of 16x16), 64 MFMA/K-tile/wave.
// LDS = 128 KiB: A[2bufs][256][64] at 0, B[2bufs][256][64] at 65536.
//
// LDS layout (T2 st_16x32): tile stored as row-major grid of 16x32-element
// subtiles (1024 B each, id = (r>>4)*2 + (k>>5)); within a subtile
// woff = (r&15)*64 + (k&31)*2, then woff ^= ((r>>3)&1)<<5. Readers use this
// formula; global_load_lds writes LINEARLY (chunk i -> byte i*16), so the
// stager loads from the INVERSE-swizzled global chunk (rule 21): for linear
// chunk j within a subtile, jo = j ^ (((j>>5)&1)<<1) gives the source
// (row,k) chunk. Reduces the 16-way fragment-read conflict to ~4-way.
//
// Phase schedule per K-tile kt (buf = kt&1), hazard-checked:
//  P1: ds-read a[m0..3]x{k0,k1} + b[n0,n1]x{k0,k1};  stage A(kt+1) h0 -> buf^1
//  P2: ds-read b[n2,n3]x{k0,k1};                     stage A(kt+1) h1 -> buf^1
//  P3: ds-read a[m4..7]x{k0,k1};                     stage B(kt+2) h0 -> buf
//  P4: (no reads)                                    stage B(kt+2) h1 -> buf
//      vmcnt(4)  <- leaves only P3/P4's B(kt+2) halves in flight; forces
//                   A(kt+1) (issued P1/P2) + B(kt+1) (issued last iter) landed
// Each phase: [reads | stage-issue] barrier; lgkmcnt(0)+sched_barrier;
// setprio(1); 16 MFMA (one C-quadrant x BK); setprio(0); barrier.
// WAR safety: every staged region's last ds_read is >=1 closing-barrier
// earlier (A^1 halves: P3 of prior tile; buf B h0/h1: P2 of this tile), and
// a wave's reads complete (its lgkmcnt(0)) before it reaches that barrier.
// ---------------------------------------------------------------------------
template <int MODE, typename OutT>
__global__ __launch_bounds__(512, 2)
void gemm8(const short* __restrict__ A, int lda, long aBatch,
           const short* __restrict__ B, int ldb, long bBatch,
           OutT* __restrict__ C, int ldc, long cBatch,
           int K, int ntilesN, int tilesPerHead,
           const float* __restrict__ bias, int pBatch)
{
    __shared__ __attribute__((aligned(128))) char lds[131072];

    const int tid = threadIdx.x;
    const int w   = tid >> 6;
    const int l   = tid & 63;
    const int wm  = w >> 2;       // 0..1 : which 128-row half this wave owns
    const int wn  = w & 3;        // 0..3 : which 64-col quarter

    // T1: bijective XCD swizzle (gridDim.x % 8 == 0 for all our launches)
    const int nwg  = gridDim.x;
    const int cpx  = nwg >> 3;
    const int bid  = blockIdx.x;
    const int swz  = (bid & 7) * cpx + (bid >> 3);
    const int head = swz / tilesPerHead;
    const int tile = swz - head * tilesPerHead;
    const int mt   = tile / ntilesN;
    const int nt   = tile - mt * ntilesN;
    const int m0   = mt * 256;
    const int n0   = nt * 256;

    const short* Ag = A + (long)head * aBatch + (long)m0 * lda;
    const short* Bg = B + (long)head * bBatch + (long)n0 * ldb;
    C += (long)head * cBatch;
    const float* pb = bias + (long)head * pBatch;

    // staging: this thread's 2 chunks per half-tile (inverse-swizzled source)
    int rowL[2], k0L[2];
#pragma unroll
    for (int li = 0; li < 2; ++li) {
        const int i  = tid + li * 512;               // linear chunk 0..1023
        const int id = i >> 6;                       // subtile 0..15
        const int j  = i & 63;                       // chunk within subtile
        const int jo = j ^ (((j >> 5) & 1) << 1);    // un-swizzle
        rowL[li] = (id >> 1) * 16 + (jo >> 2);       // 0..127
        k0L[li]  = (id & 1) * 32 + (jo & 3) * 8;     // 0..56
    }
    const int ldsW = w * 1024;   // wave's chunk base within a half region

    // fragment read offset within a subtile (swizzled)
    const int lrow    = l & 15;
    const int fragoff = (lrow * 64 + (l >> 4) * 16) ^ (((lrow >> 3) & 1) << 5);

    const int nkt = K >> 6;

#define STAGE(srcbase, ld_, kt_, h_, region)                                     \
    do {                                                                         \
        gld_lds16((srcbase) + (long)((h_) * 128 + rowL[0]) * (ld_) +             \
                      (kt_) * 64 + k0L[0],                                       \
                  (region) + (h_) * 16384 + ldsW);                               \
        gld_lds16((srcbase) + (long)((h_) * 128 + rowL[1]) * (ld_) +             \
                      (kt_) * 64 + k0L[1],                                       \
                  (region) + (h_) * 16384 + ldsW + 8192);                        \
    } while (0)

    char* const ldsA0 = lds;
    char* const ldsB0 = lds + 65536;

    // ---- prologue: tile 0 fully + B halves of tile 1 (matches steady state)
    STAGE(Ag, lda, 0, 0, ldsA0);
    STAGE(Ag, lda, 0, 1, ldsA0);
    STAGE(Bg, ldb, 0, 0, ldsB0);
    STAGE(Bg, ldb, 0, 1, ldsB0);
    if (nkt > 1) {
        STAGE(Bg, ldb, 1, 0, ldsB0 + 32768);
        STAGE(Bg, ldb, 1, 1, ldsB0 + 32768);
        asm volatile("s_waitcnt vmcnt(4)" ::: "memory");
    } else {
        asm volatile("s_waitcnt vmcnt(0)" ::: "memory");
    }
    __builtin_amdgcn_sched_barrier(0);
    __builtin_amdgcn_s_barrier();

    floatx4 acc[8][4] = {};
    bf16x8 a[4][2], b[4][2];
    const int aSr = wm * 8;   // A subtile-row base
    const int bSr = wn * 4;   // B subtile-row base

    for (int kt = 0; kt < nkt; ++kt) {
        char* const ldsA  = ldsA0 + (kt & 1) * 32768;
        char* const ldsB  = ldsB0 + (kt & 1) * 32768;
        char* const ldsAn = ldsA0 + ((kt & 1) ^ 1) * 32768;

        // ---------------- P1 : quadrant (m0-3, n0-1) ----------------
#pragma unroll
        for (int m = 0; m < 4; ++m) {
            a[m][0] = *(const bf16x8*)(ldsA + ((aSr + m) * 2 + 0) * 1024 + fragoff);
            a[m][1] = *(const bf16x8*)(ldsA + ((aSr + m) * 2 + 1) * 1024 + fragoff);
        }
#pragma unroll
        for (int n = 0; n < 2; ++n) {
            b[n][0] = *(const bf16x8*)(ldsB + ((bSr + n) * 2 + 0) * 1024 + fragoff);
            b[n][1] = *(const bf16x8*)(ldsB + ((bSr + n) * 2 + 1) * 1024 + fragoff);
        }
        if (kt + 1 < nkt) { STAGE(Ag, lda, kt + 1, 0, ldsAn); }
        __builtin_amdgcn_s_barrier();
        asm volatile("s_waitcnt lgkmcnt(0)" ::: "memory");
        __builtin_amdgcn_sched_barrier(0);
        __builtin_amdgcn_s_setprio(1);
#pragma unroll
        for (int m = 0; m < 4; ++m)
#pragma unroll
            for (int n = 0; n < 2; ++n)
#pragma unroll
                for (int ks = 0; ks < 2; ++ks)
                    acc[m][n] = __builtin_amdgcn_mfma_f32_16x16x32_bf16(
                        a[m][ks], b[n][ks], acc[m][n], 0, 0, 0);
        __builtin_amdgcn_s_setprio(0);
        __builtin_amdgcn_s_barrier();

        // ---------------- P2 : quadrant (m0-3, n2-3) ----------------
#pragma unroll
        for (int n = 2; n < 4; ++n) {
            b[n][0] = *(const bf16x8*)(ldsB + ((bSr + n) * 2 + 0) * 1024 + fragoff);
            b[n][1] = *(const bf16x8*)(ldsB + ((bSr + n) * 2 + 1) * 1024 + fragoff);
        }
        if (kt + 1 < nkt) { STAGE(Ag, lda, kt + 1, 1, ldsAn); }
        __builtin_amdgcn_s_barrier();
        asm volatile("s_waitcnt lgkmcnt(0)" ::: "memory");
        __builtin_amdgcn_sched_barrier(0);
        __builtin_amdgcn_s_setprio(1);
#pragma unroll
        for (int m = 0; m < 4; ++m)
#pragma unroll
            for (int n = 2; n < 4; ++n)
#pragma unroll
                for (int ks = 0; ks < 2; ++ks)
                    acc[m][n] = __builtin_amdgcn_mfma_f32_16x16x32_bf16(
                        a[m][ks], b[n][ks], acc[m][n], 0, 0, 0);
        __builtin_amdgcn_s_setprio(0);
        __builtin_amdgcn_s_barrier();

        // ---------------- P3 : quadrant (m4-7, n2-3) ----------------
#pragma unroll
        for (int m = 0; m < 4; ++m) {
            a[m][0] = *(const bf16x8*)(ldsA + ((aSr + 4 + m) * 2 + 0) * 1024 + fragoff);
            a[m][1] = *(const bf16x8*)(ldsA + ((aSr + 4 + m) * 2 + 1) * 1024 + fragoff);
        }
        if (kt + 2 < nkt) { STAGE(Bg, ldb, kt + 2, 0, ldsB); }
        __builtin_amdgcn_s_barrier();
        asm volatile("s_waitcnt lgkmcnt(0)" ::: "memory");
        __builtin_amdgcn_sched_barrier(0);
        __builtin_amdgcn_s_setprio(1);
#pragma unroll
        for (int m = 0; m < 4; ++m)
#pragma unroll
            for (int n = 2; n < 4; ++n)
#pragma unroll
                for (int ks = 0; ks < 2; ++ks)
                    acc[m + 4][n] = __builtin_amdgcn_mfma_f32_16x16x32_bf16(
                        a[m][ks], b[n][ks], acc[m + 4][n], 0, 0, 0);
        __builtin_amdgcn_s_setprio(0);
        __builtin_amdgcn_s_barrier();

        // ---------------- P4 : quadrant (m4-7, n0-1) ----------------
        if (kt + 2 < nkt) { STAGE(Bg, ldb, kt + 2, 1, ldsB); }
        __builtin_amdgcn_s_setprio(1);
#pragma unroll
        for (int m = 0; m < 4; ++m)
#pragma unroll
            for (int n = 0; n < 2; ++n)
#pragma unroll
                for (int ks = 0; ks < 2; ++ks)
                    acc[m + 4][n] = __builtin_amdgcn_mfma_f32_16x16x32_bf16(
                        a[m][ks], b[n][ks], acc[m + 4][n], 0, 0, 0);
        __builtin_amdgcn_s_setprio(0);
        if (kt + 2 < nkt) {
            asm volatile("s_waitcnt vmcnt(4)" ::: "memory");   // counted, never 0
        } else if (kt + 1 < nkt) {
            asm volatile("s_waitcnt vmcnt(0)" ::: "memory");   // drain for last tile
        }
        __builtin_amdgcn_sched_barrier(0);
        __builtin_amdgcn_s_barrier();
    }
#undef STAGE

    // ---- epilogue
    const int erow = (l >> 4) * 4;
    const int ecol = l & 15;
#pragma unroll
    for (int n = 0; n < 4; ++n) {
        const int nj = n0 + wn * 64 + n * 16 + ecol;
        const float shift = pb[nj];
#pragma unroll
        for (int m = 0; m < 8; ++m) {
            const long mi = m0 + wm * 128 + m * 16 + erow;
#pragma unroll
            for (int r = 0; r < 4; ++r) {
                float v = acc[m][n][r] + shift;
                if constexpr (MODE == 1) v = fmaxf(v, 0.f);
                const long idx = (mi + r) * (long)ldc + nj;
                if constexpr (sizeof(OutT) == 2) C[idx] = (OutT)f2bf(v);
                else                             C[idx] = (OutT)v;
            }
        }
    }
}

// ---------------------------------------------------------------------------
// Fast fp32 [R][C] -> bf16 [C][R] transpose, R and C multiples of 64, batched.
// ---------------------------------------------------------------------------
__global__ __launch_bounds__(256)
void transpose64(const float* __restrict__ in, unsigned short* __restrict__ out,
                 int R, int C, long inBatch, long outBatch)
{
    __shared__ unsigned short lt[64 * 68];
    in  += (long)blockIdx.z * inBatch;
    out += (long)blockIdx.z * outBatch;
    const int c0 = blockIdx.x * 64;
    const int r0 = blockIdx.y * 64;
    const int t  = threadIdx.x;

    {
        const int rb = t >> 4;
        const int cg = (t & 15) * 4;
        floatx4 v[4];
#pragma unroll
        for (int i = 0; i < 4; ++i)
            v[i] = *(const floatx4*)&in[(long)(r0 + rb * 4 + i) * C + c0 + cg];
#pragma unroll
        for (int j = 0; j < 4; ++j) {
            ushortx4 col;
#pragma unroll
            for (int i = 0; i < 4; ++i) col[i] = f2bf(v[i][j]);
            *(ushortx4*)&lt[(cg + j) * 68 + rb * 4] = col;
        }
    }
    __syncthreads();

#pragma unroll
    for (int it = 0; it < 2; ++it) {
        const int idx = t + it * 256;
        const int c   = idx >> 3;
        const int rc  = idx & 7;
        ushortx4 lo = *(const ushortx4*)&lt[c * 68 + rc * 8];
        ushortx4 hi = *(const ushortx4*)&lt[c * 68 + rc * 8 + 4];
        ushortx8 o;
        o[0] = lo[0]; o[1] = lo[1]; o[2] = lo[2]; o[3] = lo[3];
        o[4] = hi[0]; o[5] = hi[1]; o[6] = hi[2]; o[7] = hi[3];
        *(ushortx8*)&out[(long)(c0 + c) * R + r0 + rc * 8] = o;
    }
}

// ---------------------------------------------------------------------------
// slow-path transpose (tiny W0 with R=200 -> Rpad=224)
// ---------------------------------------------------------------------------
__global__ void transpose_f32_bf16(const float* __restrict__ in, short* __restrict__ out,
                                   int R, int C, int Rpad, long inBatch, long outBatch)
{
    __shared__ float tile[32][33];
    in  += (long)blockIdx.z * inBatch;
    out += (long)blockIdx.z * outBatch;
    const int c0 = blockIdx.x * 32;
    const int r0 = blockIdx.y * 32;
    const int tx = threadIdx.x, ty = threadIdx.y;
#pragma unroll
    for (int rr = 0; rr < 4; ++rr) {
        const int r = r0 + ty + rr * 8;
        float v = 0.f;
        if (r < R) v = in[(long)r * C + c0 + tx];
        tile[ty + rr * 8][tx] = v;
    }
    __syncthreads();
#pragma unroll
    for (int rr = 0; rr < 4; ++rr) {
        const int oc = ty + rr * 8;
        out[(long)(c0 + oc) * Rpad + r0 + tx] = (short)f2bf(tile[tx][oc]);
    }
}

// fp32 [R][C] -> bf16 [R][Cpad], zero-padded cols
__global__ void pad_convert(const float* __restrict__ in, short* __restrict__ out,
                            int C, int Cpad, int total)
{
    const int idx = blockIdx.x * 256 + threadIdx.x;
    if (idx >= total) return;
    const int r = idx / Cpad, c = idx % Cpad;
    out[idx] = (short)f2bf(c < C ? in[(long)r * C + c] : 0.f);
}

// ---------------------------------------------------------------------------

extern "C" void kernel_launch(void* const* d_in, const int* in_sizes, int n_in,
                              void* d_out, int out_size, void* d_ws, size_t ws_size,
                              hipStream_t stream)
{
    const float* x   = (const float*)d_in[0];
    const float* W0  = (const float*)d_in[1];
    const float* b0  = (const float*)d_in[2];
    const float* g0  = (const float*)d_in[3];
    const float* be0 = (const float*)d_in[4];
    const float* m0  = (const float*)d_in[5];
    const float* v0  = (const float*)d_in[6];
    const float* W1  = (const float*)d_in[7];
    const float* b1  = (const float*)d_in[8];
    const float* g1  = (const float*)d_in[9];
    const float* be1 = (const float*)d_in[10];
    const float* m1  = (const float*)d_in[11];
    const float* v1  = (const float*)d_in[12];
    const float* HW1 = (const float*)d_in[13];
    const float* Hb1 = (const float*)d_in[14];
    const float* HW2 = (const float*)d_in[15];
    const float* Hb2 = (const float*)d_in[16];
    float* out = (float*)d_out;

    char* ws = (char*)d_ws;
    size_t off = 0;
    short* xb   = (short*)(ws + off); off += (size_t)1024 * 224 * 2;
    short* W0T  = (short*)(ws + off); off += (size_t)2048 * 224 * 2;
    short* W1T  = (short*)(ws + off); off += (size_t)1024 * 2048 * 2;
    short* HW1T = (short*)(ws + off); off += (size_t)128 * 512 * 1024 * 2;
    short* HW2T = (short*)(ws + off); off += (size_t)128 * 256 * 512 * 2;
    short* h    = (short*)(ws + off); off += (size_t)1024 * 2048 * 2;
    short* fts  = (short*)(ws + off); off += (size_t)1024 * 1024 * 2;
    short* z    = (short*)(ws + off); off += (size_t)1024 * 128 * 512 * 2;

    // bf16 conversions / transposes
    pad_convert<<<dim3((1024 * 224) / 256), dim3(256), 0, stream>>>(x, xb, 200, 224, 1024 * 224);
    transpose_f32_bf16<<<dim3(64, 7, 1), dim3(32, 8), 0, stream>>>(W0, W0T, 200, 2048, 224, 0, 0);
    transpose64<<<dim3(16, 32, 1), dim3(256), 0, stream>>>(
        W1, (unsigned short*)W1T, 2048, 1024, 0, 0);
    transpose64<<<dim3(8, 16, 128), dim3(256), 0, stream>>>(
        HW1, (unsigned short*)HW1T, 1024, 512, (long)1024 * 512, (long)512 * 1024);
    transpose64<<<dim3(4, 8, 128), dim3(256), 0, stream>>>(
        HW2, (unsigned short*)HW2T, 512, 256, (long)512 * 256, (long)256 * 512);

    // trunk: h = relu(BN0(x@W0 + b0))   M=1024 N=2048 K=224
    gemm_bt<0, short><<<dim3(8 * 16, 1), dim3(256), 0, stream>>>(
        xb, 224, 0, W0T, 224, 0, h, 2048, 0, 224, 16, b0, g0, be0, m0, v0, 0);
    // trunk: feats = relu(BN1(h@W1 + b1))   M=1024 N=1024 K=2048
    gemm_bt<0, short><<<dim3(8 * 8, 1), dim3(256), 0, stream>>>(
        h, 2048, 0, W1T, 2048, 0, fts, 1024, 0, 2048, 8, b1, g1, be1, m1, v1, 0);
    // heads layer 1: z = relu(feats@HW1[n] + Hb1[n])  per head M=1024 N=512 K=1024
    // grid = 8 tiles/head * 128 heads = 1024 (%8==0 for XCD swizzle)
    gemm8<1, short><<<dim3(8 * 128), dim3(512), 0, stream>>>(
        fts, 1024, 0, HW1T, 1024, (long)512 * 1024, z, 128 * 512, 512,
        1024, 2, 8, Hb1, 512);
    // heads layer 2: out = z@HW2[n] + Hb2[n]  per head M=1024 N=256 K=512
    // grid = 4 tiles/head * 128 heads = 512
    gemm8<2, float><<<dim3(4 * 128), dim3(512), 0, stream>>>(
        z, 128 * 512, 512, HW2T, 512, (long)256 * 512, out, 128 * 256, 256,
        512, 1, 4, Hb2, 256);

    (void)in_sizes; (void)n_in; (void)out_size; (void)ws_size;
}